// Round 1
// baseline (166.907 us; speedup 1.0000x reference)
//
#include <hip/hip_runtime.h>

#define N_NODES 50000
#define N_EDGES 200000
#define S_DIM   8
#define F_DIM   32      // F_IN == F == 32
#define G_SEG   512
#define P_PAIRS 1024
#define A_COLS  288     // 9 * 32 : 8 Wk rows + 1 bk row, each giving 32 outputs

// ---------------------------------------------------------------------------
// K1: per-node GEMM.
//   A[n][s*32+o] = sum_i h[n][i] * Wk[s][i*32+o]   (s = 0..7)
//   A[n][8*32+o] = sum_i h[n][i] * bk[i*32+o]      (bias-of-kernel row, e'_8 = 1)
//   agg[n][o]    = sum_i h[n][i] * root[i][o] + b[o]   (init for the scatter)
// LAYER==0: h = x[n, 0..31] (row stride 33). LAYER==1: h = relu(prev agg).
// Block: 320 threads (5 waves), one column c each; 64 nodes per block.
// Weights live in registers (32 per thread); h-tile in LDS (broadcast reads).
// ---------------------------------------------------------------------------
template <int LAYER>
__global__ __launch_bounds__(320)
void node_gemm(const float* __restrict__ hsrc,
               const float* __restrict__ Wk, const float* __restrict__ bk,
               const float* __restrict__ root, const float* __restrict__ bias,
               float* __restrict__ A, float* __restrict__ agg)
{
    const int NB = 64;
    __shared__ float hh[NB][F_DIM];

    const int nb   = blockIdx.x * NB;
    const int nmax = (N_NODES - nb < NB) ? (N_NODES - nb) : NB;

    for (int idx = threadIdx.x; idx < nmax * F_DIM; idx += 320) {
        const int n = idx >> 5, i = idx & 31;
        float v;
        if (LAYER == 0) {
            v = hsrc[(size_t)(nb + n) * (F_DIM + 1) + i];   // x has 33 cols
        } else {
            v = hsrc[(size_t)(nb + n) * F_DIM + i];
            v = v > 0.f ? v : 0.f;                          // fused relu
        }
        hh[n][i] = v;
    }
    __syncthreads();

    const int c = threadIdx.x;        // 0..319
    float w[F_DIM];
    float init = 0.f;
    if (c < 256) {                    // Wk rows
        const int s = c >> 5, o = c & 31;
        #pragma unroll
        for (int i = 0; i < F_DIM; ++i) w[i] = Wk[s * (F_DIM * F_DIM) + i * F_DIM + o];
    } else if (c < A_COLS) {          // bk row
        const int o = c & 31;
        #pragma unroll
        for (int i = 0; i < F_DIM; ++i) w[i] = bk[i * F_DIM + o];
    } else {                          // root + bias -> agg init
        const int o = c - A_COLS;
        #pragma unroll
        for (int i = 0; i < F_DIM; ++i) w[i] = root[i * F_DIM + o];
        init = bias[o];
    }

    for (int n = 0; n < nmax; ++n) {
        float acc = init;
        #pragma unroll
        for (int i = 0; i < F_DIM; ++i) acc += hh[n][i] * w[i];
        if (c < A_COLS) A[(size_t)(nb + n) * A_COLS + c] = acc;
        else            agg[(size_t)(nb + n) * F_DIM + (c - A_COLS)] = acc;
    }
}

// ---------------------------------------------------------------------------
// K2: edge scatter.  32 lanes per edge, lane o computes
//   msg[o] = A[src][8*32+o] + sum_s e[edge][s] * A[src][s*32+o]
// then atomicAdd into agg[tgt][o].
// ---------------------------------------------------------------------------
__global__ __launch_bounds__(256)
void edge_msg(const float* __restrict__ A, const float* __restrict__ evec,
              const int* __restrict__ src, const int* __restrict__ tgt,
              float* __restrict__ agg)
{
    const int gid = blockIdx.x * 256 + threadIdx.x;
    const int e   = gid >> 5;
    const int o   = gid & 31;
    if (e >= N_EDGES) return;

    const int   sn = src[e];
    const int   tn = tgt[e];
    const float* Ap = A + (size_t)sn * A_COLS + o;

    float msg = Ap[8 * F_DIM];            // bk row (implicit e'_8 = 1)
    #pragma unroll
    for (int s = 0; s < S_DIM; ++s)
        msg += evec[(size_t)e * S_DIM + s] * Ap[s * F_DIM];

    atomicAdd(&agg[(size_t)tn * F_DIM + o], msg);
}

// ---------------------------------------------------------------------------
// K3: h2 = trunc(relu(agg2)); pooled[seg[n]][o] += h2[n][o]
// ---------------------------------------------------------------------------
__global__ __launch_bounds__(256)
void pool_kernel(const float* __restrict__ agg2, const int* __restrict__ seg,
                 float* __restrict__ pooled)
{
    const int gid = blockIdx.x * 256 + threadIdx.x;
    if (gid >= N_NODES * F_DIM) return;
    const int n = gid >> 5, o = gid & 31;
    float v = agg2[gid];
    v = v > 0.f ? v : 0.f;
    v = truncf(v);
    atomicAdd(&pooled[(size_t)seg[n] * F_DIM + o], v);
}

// ---------------------------------------------------------------------------
// K4: out[g] = relu(pooled[g] . Wd + bd); result[p] = out[ib[p]] - out[ia[p]]
// Single block.
// ---------------------------------------------------------------------------
__global__ __launch_bounds__(512)
void head_kernel(const float* __restrict__ pooled, const float* __restrict__ Wd,
                 const float* __restrict__ bd, const int* __restrict__ ia,
                 const int* __restrict__ ib, float* __restrict__ out)
{
    __shared__ float og[G_SEG];
    const int g = threadIdx.x;
    if (g < G_SEG) {
        float acc = bd[0];
        #pragma unroll
        for (int i = 0; i < F_DIM; ++i) acc += pooled[(size_t)g * F_DIM + i] * Wd[i];
        og[g] = acc > 0.f ? acc : 0.f;
    }
    __syncthreads();
    for (int p = threadIdx.x; p < P_PAIRS; p += 512)
        out[p] = og[ib[p]] - og[ia[p]];
}

// ---------------------------------------------------------------------------
extern "C" void kernel_launch(void* const* d_in, const int* in_sizes, int n_in,
                              void* d_out, int out_size, void* d_ws, size_t ws_size,
                              hipStream_t stream)
{
    const float* x    = (const float*)d_in[0];
    const float* e    = (const float*)d_in[1];
    const int*   src  = (const int*)d_in[2];
    const int*   tgt  = (const int*)d_in[3];
    const int*   seg  = (const int*)d_in[4];
    const int*   ia   = (const int*)d_in[5];
    const int*   ib   = (const int*)d_in[6];
    const float* Wk1  = (const float*)d_in[7];
    const float* bk1  = (const float*)d_in[8];
    const float* root1= (const float*)d_in[9];
    const float* b1   = (const float*)d_in[10];
    const float* Wk2  = (const float*)d_in[11];
    const float* bk2  = (const float*)d_in[12];
    const float* root2= (const float*)d_in[13];
    const float* b2   = (const float*)d_in[14];
    const float* Wd   = (const float*)d_in[15];
    const float* bd   = (const float*)d_in[16];
    float* out = (float*)d_out;

    float* A      = (float*)d_ws;                       // 50000*288 f32 = 57.6 MB
    float* ag1    = A   + (size_t)N_NODES * A_COLS;     // 6.4 MB
    float* ag2    = ag1 + (size_t)N_NODES * F_DIM;      // 6.4 MB
    float* pooled = ag2 + (size_t)N_NODES * F_DIM;      // 64 KB

    hipMemsetAsync(pooled, 0, (size_t)G_SEG * F_DIM * sizeof(float), stream);

    const int nblk = (N_NODES + 63) / 64;
    const int eblk = (N_EDGES * 32) / 256;

    node_gemm<0><<<nblk, 320, 0, stream>>>(x,   Wk1, bk1, root1, b1, A, ag1);
    edge_msg   <<<eblk, 256, 0, stream>>>(A, e, src, tgt, ag1);
    node_gemm<1><<<nblk, 320, 0, stream>>>(ag1, Wk2, bk2, root2, b2, A, ag2);
    edge_msg   <<<eblk, 256, 0, stream>>>(A, e, src, tgt, ag2);
    pool_kernel<<<(N_NODES * F_DIM + 255) / 256, 256, 0, stream>>>(ag2, seg, pooled);
    head_kernel<<<1, 512, 0, stream>>>(pooled, Wd, bd, ia, ib, out);
}

// Round 2
// 164.744 us; speedup vs baseline: 1.0131x; 1.0131x over previous
//
#include <hip/hip_runtime.h>

#define N_NODES 50000
#define N_EDGES 200000
#define S_DIM   8
#define F_DIM   32      // F_IN == F == 32
#define G_SEG   512
#define P_PAIRS 1024
#define A_COLS  288     // 9 * 32 : 8 Wk rows + 1 bk row, each giving 32 outputs

// ---------------------------------------------------------------------------
// K0: zero the pooled buffer (custom — hipMemsetAsync's fill kernel costs 39us!)
// ---------------------------------------------------------------------------
__global__ __launch_bounds__(256)
void zero_pooled(float* __restrict__ pooled)
{
    const int gid = blockIdx.x * 256 + threadIdx.x;
    if (gid < G_SEG * F_DIM) pooled[gid] = 0.f;
}

// ---------------------------------------------------------------------------
// K1: per-node GEMM.
//   A[n][s*32+o] = sum_i h[n][i] * Wk[s][i*32+o]   (s = 0..7)
//   A[n][8*32+o] = sum_i h[n][i] * bk[i*32+o]      (bias-of-kernel row, e'_8=1)
//   agg[n][o]    = sum_i h[n][i] * root[i][o] + b[o]   (init for the scatter)
// LAYER==0: h = x[n, 0..31] (row stride 33). LAYER==1: h = relu(prev agg).
// Block: 320 threads (5 waves), one column c each; 64 nodes per block.
// Weights in registers (32/thread); h-tile in LDS (broadcast float4 reads).
// ---------------------------------------------------------------------------
template <int LAYER>
__global__ __launch_bounds__(320)
void node_gemm(const float* __restrict__ hsrc,
               const float* __restrict__ Wk, const float* __restrict__ bk,
               const float* __restrict__ root, const float* __restrict__ bias,
               float* __restrict__ A, float* __restrict__ agg)
{
    const int NB = 64;
    __shared__ float hh[NB][F_DIM];   // rows 128B-aligned -> float4-clean

    const int nb   = blockIdx.x * NB;
    const int nmax = (N_NODES - nb < NB) ? (N_NODES - nb) : NB;

    if (LAYER == 0) {
        // x rows are 33 floats (132B) — not 16B aligned; scalar coalesced loads
        for (int idx = threadIdx.x; idx < nmax * F_DIM; idx += 320) {
            const int n = idx >> 5, i = idx & 31;
            hh[n][i] = hsrc[(size_t)(nb + n) * (F_DIM + 1) + i];
        }
    } else {
        // prev agg rows are 32 floats, 128B aligned -> float4 + fused relu
        const float4* src4 = (const float4*)(hsrc + (size_t)nb * F_DIM);
        for (int idx = threadIdx.x; idx < nmax * (F_DIM / 4); idx += 320) {
            float4 v = src4[idx];
            v.x = v.x > 0.f ? v.x : 0.f;
            v.y = v.y > 0.f ? v.y : 0.f;
            v.z = v.z > 0.f ? v.z : 0.f;
            v.w = v.w > 0.f ? v.w : 0.f;
            ((float4*)hh)[idx] = v;
        }
    }
    __syncthreads();

    const int c = threadIdx.x;        // 0..319
    float w[F_DIM];
    float init = 0.f;
    if (c < 256) {                    // Wk rows
        const int s = c >> 5, o = c & 31;
        #pragma unroll
        for (int i = 0; i < F_DIM; ++i) w[i] = Wk[s * (F_DIM * F_DIM) + i * F_DIM + o];
    } else if (c < A_COLS) {          // bk row
        const int o = c & 31;
        #pragma unroll
        for (int i = 0; i < F_DIM; ++i) w[i] = bk[i * F_DIM + o];
    } else {                          // root + bias -> agg init
        const int o = c - A_COLS;
        #pragma unroll
        for (int i = 0; i < F_DIM; ++i) w[i] = root[i * F_DIM + o];
        init = bias[o];
    }

    for (int n = 0; n < nmax; ++n) {
        const float4* hv = (const float4*)hh[n];
        float acc = init;
        #pragma unroll
        for (int i4 = 0; i4 < F_DIM / 4; ++i4) {
            float4 h4 = hv[i4];
            acc += h4.x * w[4*i4]   + h4.y * w[4*i4+1]
                 + h4.z * w[4*i4+2] + h4.w * w[4*i4+3];
        }
        if (c < A_COLS) A[(size_t)(nb + n) * A_COLS + c] = acc;
        else            agg[(size_t)(nb + n) * F_DIM + (c - A_COLS)] = acc;
    }
}

// ---------------------------------------------------------------------------
// K2: edge scatter.  32 lanes per edge, lane o computes
//   msg[o] = A[src][8*32+o] + sum_s e[edge][s] * A[src][s*32+o]
// then atomicAdd into agg[tgt][o].
// ---------------------------------------------------------------------------
__global__ __launch_bounds__(256)
void edge_msg(const float* __restrict__ A, const float* __restrict__ evec,
              const int* __restrict__ src, const int* __restrict__ tgt,
              float* __restrict__ agg)
{
    const int gid = blockIdx.x * 256 + threadIdx.x;
    const int e   = gid >> 5;
    const int o   = gid & 31;
    if (e >= N_EDGES) return;

    const int   sn = src[e];
    const int   tn = tgt[e];
    const float* Ap = A + (size_t)sn * A_COLS + o;

    float msg = Ap[8 * F_DIM];            // bk row (implicit e'_8 = 1)
    #pragma unroll
    for (int s = 0; s < S_DIM; ++s)
        msg += evec[(size_t)e * S_DIM + s] * Ap[s * F_DIM];

    atomicAdd(&agg[(size_t)tn * F_DIM + o], msg);
}

// ---------------------------------------------------------------------------
// K3: h2 = trunc(relu(agg2)); pooled[seg[n]][o] += h2[n][o]
// ---------------------------------------------------------------------------
__global__ __launch_bounds__(256)
void pool_kernel(const float* __restrict__ agg2, const int* __restrict__ seg,
                 float* __restrict__ pooled)
{
    const int gid = blockIdx.x * 256 + threadIdx.x;
    if (gid >= N_NODES * F_DIM) return;
    const int n = gid >> 5, o = gid & 31;
    float v = agg2[gid];
    v = v > 0.f ? v : 0.f;
    v = truncf(v);
    atomicAdd(&pooled[(size_t)seg[n] * F_DIM + o], v);
}

// ---------------------------------------------------------------------------
// K4: out[g] = relu(pooled[g] . Wd + bd); result[p] = out[ib[p]] - out[ia[p]]
// Single block.
// ---------------------------------------------------------------------------
__global__ __launch_bounds__(512)
void head_kernel(const float* __restrict__ pooled, const float* __restrict__ Wd,
                 const float* __restrict__ bd, const int* __restrict__ ia,
                 const int* __restrict__ ib, float* __restrict__ out)
{
    __shared__ float og[G_SEG];
    const int g = threadIdx.x;
    if (g < G_SEG) {
        float acc = bd[0];
        #pragma unroll
        for (int i = 0; i < F_DIM; ++i) acc += pooled[(size_t)g * F_DIM + i] * Wd[i];
        og[g] = acc > 0.f ? acc : 0.f;
    }
    __syncthreads();
    for (int p = threadIdx.x; p < P_PAIRS; p += 512)
        out[p] = og[ib[p]] - og[ia[p]];
}

// ---------------------------------------------------------------------------
extern "C" void kernel_launch(void* const* d_in, const int* in_sizes, int n_in,
                              void* d_out, int out_size, void* d_ws, size_t ws_size,
                              hipStream_t stream)
{
    const float* x    = (const float*)d_in[0];
    const float* e    = (const float*)d_in[1];
    const int*   src  = (const int*)d_in[2];
    const int*   tgt  = (const int*)d_in[3];
    const int*   seg  = (const int*)d_in[4];
    const int*   ia   = (const int*)d_in[5];
    const int*   ib   = (const int*)d_in[6];
    const float* Wk1  = (const float*)d_in[7];
    const float* bk1  = (const float*)d_in[8];
    const float* root1= (const float*)d_in[9];
    const float* b1   = (const float*)d_in[10];
    const float* Wk2  = (const float*)d_in[11];
    const float* bk2  = (const float*)d_in[12];
    const float* root2= (const float*)d_in[13];
    const float* b2   = (const float*)d_in[14];
    const float* Wd   = (const float*)d_in[15];
    const float* bd   = (const float*)d_in[16];
    float* out = (float*)d_out;

    float* A      = (float*)d_ws;                       // 50000*288 f32 = 57.6 MB
    float* ag1    = A   + (size_t)N_NODES * A_COLS;     // 6.4 MB
    float* ag2    = ag1 + (size_t)N_NODES * F_DIM;      // 6.4 MB
    float* pooled = ag2 + (size_t)N_NODES * F_DIM;      // 64 KB

    const int nblk = (N_NODES + 63) / 64;
    const int eblk = (N_EDGES * 32) / 256;

    zero_pooled<<<(G_SEG * F_DIM + 255) / 256, 256, 0, stream>>>(pooled);
    node_gemm<0><<<nblk, 320, 0, stream>>>(x,   Wk1, bk1, root1, b1, A, ag1);
    edge_msg   <<<eblk, 256, 0, stream>>>(A, e, src, tgt, ag1);
    node_gemm<1><<<nblk, 320, 0, stream>>>(ag1, Wk2, bk2, root2, b2, A, ag2);
    edge_msg   <<<eblk, 256, 0, stream>>>(A, e, src, tgt, ag2);
    pool_kernel<<<(N_NODES * F_DIM + 255) / 256, 256, 0, stream>>>(ag2, seg, pooled);
    head_kernel<<<1, 512, 0, stream>>>(pooled, Wd, bd, ia, ib, out);
}